// Round 6
// baseline (1375.492 us; speedup 1.0000x reference)
//
#include <hip/hip_runtime.h>

// VQ nearest-neighbor: argmin_k ||c_k||^2 - 2 x_n . c_k
// N=32768 rows, K=8192 codes, D=512, fp32 in, int32 indices out.
//
// Round 6: r5 structure with the X-staging bug FIXED (X restaged every
// K-step like C; r5 reused a 2-deep buffer for 16 distinct X tiles ->
// stale reads for ct>=1). Transposed 256x256 tile (A=codes, B=x-rows),
// 32x32x16 MFMA, 8 waves, per-lane top-2 fold, counted vmcnt(8) 2-phase,
// LDS XOR chunk-swizzle (conflict-free), XCD-affine split decode.

#define D_DIM 512
#define EPS_GAP 1.5e-6f
#define KSPLIT 8
#define RPB 8

typedef __attribute__((ext_vector_type(8))) short short8;
typedef __attribute__((ext_vector_type(16))) float f32x16;
typedef __attribute__((ext_vector_type(4))) unsigned short us4;

__device__ __forceinline__ unsigned short f2bf(float x) {
    unsigned u = __float_as_uint(x);
    u += 0x7fffu + ((u >> 16) & 1u);          // RNE
    return (unsigned short)(u >> 16);
}
__device__ __forceinline__ float bf2f(unsigned short h) {
    return __uint_as_float(((unsigned)h) << 16);
}

__device__ __forceinline__ void gload_lds16(const void* g, void* l) {
    __builtin_amdgcn_global_load_lds(
        (const __attribute__((address_space(1))) unsigned int*)g,
        (__attribute__((address_space(3))) unsigned int*)l, 16, 0, 0);
}

// ---- pass 0a: split X fp32 -> (hi, lo) bf16 ----
__global__ __launch_bounds__(256) void split_kernel(const float* __restrict__ src,
                                                    unsigned short* __restrict__ hi,
                                                    unsigned short* __restrict__ lo,
                                                    int n4) {
    int i = blockIdx.x * blockDim.x + threadIdx.x;
    int stride = gridDim.x * blockDim.x;
    for (; i < n4; i += stride) {
        float4 v = ((const float4*)src)[i];
        us4 h, l;
        h.x = f2bf(v.x); l.x = f2bf(v.x - bf2f(h.x));
        h.y = f2bf(v.y); l.y = f2bf(v.y - bf2f(h.y));
        h.z = f2bf(v.z); l.z = f2bf(v.z - bf2f(h.z));
        h.w = f2bf(v.w); l.w = f2bf(v.w - bf2f(h.w));
        ((us4*)hi)[i] = h;
        ((us4*)lo)[i] = l;
    }
}

// ---- pass 0b: split CB + ||c||^2 in one read (wave per code row) ----
__global__ __launch_bounds__(256) void splitcb_kernel(const float* __restrict__ cb,
                                                      unsigned short* __restrict__ hi,
                                                      unsigned short* __restrict__ lo,
                                                      float* __restrict__ sq,
                                                      int* __restrict__ cnt, int K) {
    if (blockIdx.x == 0 && threadIdx.x == 0 && cnt) *cnt = 0;
    int gtid = blockIdx.x * blockDim.x + threadIdx.x;
    int w = gtid >> 6;
    int lane = gtid & 63;
    if (w >= K) return;
    size_t base = (size_t)w * D_DIM + lane * 8;
    const float4* r4 = (const float4*)(cb + base);
    float4 u = r4[0], v = r4[1];
    float s = u.x*u.x + u.y*u.y + u.z*u.z + u.w*u.w
            + v.x*v.x + v.y*v.y + v.z*v.z + v.w*v.w;
    us4 h0, l0, h1, l1;
    h0.x = f2bf(u.x); l0.x = f2bf(u.x - bf2f(h0.x));
    h0.y = f2bf(u.y); l0.y = f2bf(u.y - bf2f(h0.y));
    h0.z = f2bf(u.z); l0.z = f2bf(u.z - bf2f(h0.z));
    h0.w = f2bf(u.w); l0.w = f2bf(u.w - bf2f(h0.w));
    h1.x = f2bf(v.x); l1.x = f2bf(v.x - bf2f(h1.x));
    h1.y = f2bf(v.y); l1.y = f2bf(v.y - bf2f(h1.y));
    h1.z = f2bf(v.z); l1.z = f2bf(v.z - bf2f(h1.z));
    h1.w = f2bf(v.w); l1.w = f2bf(v.w - bf2f(h1.w));
    ((us4*)(hi + base))[0] = h0; ((us4*)(hi + base))[1] = h1;
    ((us4*)(lo + base))[0] = l0; ((us4*)(lo + base))[1] = l1;
#pragma unroll
    for (int off = 32; off; off >>= 1) s += __shfl_xor(s, off);
    if (lane == 0) sq[w] = s;
}

// ---- pass 1: transposed MFMA dists + per-lane top-2 ----
// grid = (N/256)*KSPLIT blocks, 512 threads (8 waves: wr 2 x wcq 4).
// Output tile: 256 codes x 256 xrows. bid&7 = split (XCD-affine).
__global__ __launch_bounds__(512, 2) void vq_mfma_kernel(
        const unsigned short* __restrict__ Xh, const unsigned short* __restrict__ Xl,
        const unsigned short* __restrict__ Ch, const unsigned short* __restrict__ Cl,
        const float* __restrict__ cbs,
        float* __restrict__ pd1, int* __restrict__ pi1, float* __restrict__ pd2,
        int N, int K) {

    __shared__ unsigned short Cs_h[2][256 * 32], Cs_l[2][256 * 32];  // codes
    __shared__ unsigned short Xs_h[2][256 * 32], Xs_l[2][256 * 32];  // xrows

    const int tid  = threadIdx.x;
    const int lane = tid & 63;
    const int w    = tid >> 6;       // 0..7
    const int wr   = w >> 2;         // code half (0/1) -> codes wr*128..+127
    const int wcq  = w & 3;          // x quad (0..3)  -> xrows wcq*64..+63
    const int bid  = blockIdx.x;
    const int split     = bid & (KSPLIT - 1);
    const int rowBase   = (bid >> 3) * 256;          // x rows
    const int kPerSplit = K / KSPLIT;
    const int splitBase = split * kPerSplit;
    const int NT        = kPerSplit / 256;
    const int nSteps    = NT * 16;

    // staging: per tile, wave w covers rows w*32+(lane>>2) and +16, chunk lane&3.
    // swizzle s(r)=(r>>1)&3 -> pre-swizzled global chunk = (l&3)^((l>>3)&3).
    const int l4  = lane >> 2;
    const int swz = ((lane & 3) ^ ((lane >> 3) & 3)) * 8;
    const size_t gX0 = (size_t)(rowBase + w * 32 + l4) * D_DIM + swz;
    const size_t gC0 = (size_t)(w * 32 + l4) * D_DIM + swz;   // + codeBase*D
    const int l0 = w * 1024 + lane * 8;

    // fragment reads (32x32x16): operand row = base + (lane&31),
    // k-octet = kh*2 + (lane>>5); swizzled chunk = octet ^ ((row>>1)&3).
    const int lh = lane >> 5;
    const int rC = wr * 128 + (lane & 31);
    const int rX = wcq * 64 + (lane & 31);
    const int kp = ((lane & 31) >> 1) & 3;
    const int kOff0 = ((0 * 2 + lh) ^ kp) * 8;   // kh = 0
    const int kOff1 = ((1 * 2 + lh) ^ kp) * 8;   // kh = 1

    float d1v[2], d2v[2];
    int   i1v[2];
#pragma unroll
    for (int nf = 0; nf < 2; ++nf) { d1v[nf] = 3.4e38f; d2v[nf] = 3.4e38f; i1v[nf] = 0x7fffffff; }

    f32x16 acc[4][2];

    auto fold = [&](int ctF) {
        const int cb0 = splitBase + ctF * 256 + wr * 128 + 4 * lh;
#pragma unroll
        for (int mf = 0; mf < 4; ++mf)
#pragma unroll
            for (int rq = 0; rq < 4; ++rq) {
                float4 c2q = *(const float4*)&cbs[cb0 + mf * 32 + rq * 8];
#pragma unroll
                for (int j = 0; j < 4; ++j) {
                    const int code = cb0 + mf * 32 + rq * 8 + j;
                    const int reg  = rq * 4 + j;
                    const float c2 = (&c2q.x)[j];
#pragma unroll
                    for (int nf = 0; nf < 2; ++nf) {
                        float dist = fmaf(-2.f, acc[mf][nf][reg], c2);
                        bool lt = dist < d1v[nf];
                        d2v[nf] = lt ? d1v[nf] : fminf(d2v[nf], dist);
                        i1v[nf] = lt ? code : i1v[nf];
                        d1v[nf] = lt ? dist : d1v[nf];
                    }
                }
            }
    };

#define STAGE_C(buf, s_)                                                      \
    do { int ct_ = (s_) >> 4, kt_ = (s_) & 15;                                \
        size_t cb_ = (size_t)(splitBase + ct_ * 256) * D_DIM + gC0 + kt_ * 32;\
        gload_lds16(Ch + cb_,                &Cs_h[buf][l0]);                 \
        gload_lds16(Ch + cb_ + 16 * D_DIM,   &Cs_h[buf][l0 + 512]);           \
        gload_lds16(Cl + cb_,                &Cs_l[buf][l0]);                 \
        gload_lds16(Cl + cb_ + 16 * D_DIM,   &Cs_l[buf][l0 + 512]);           \
    } while (0)
#define STAGE_X(buf, s_)                                                      \
    do { int kt_ = (s_) & 15;                                                 \
        size_t xb_ = gX0 + kt_ * 32;                                          \
        gload_lds16(Xh + xb_,                &Xs_h[buf][l0]);                 \
        gload_lds16(Xh + xb_ + 16 * D_DIM,   &Xs_h[buf][l0 + 512]);           \
        gload_lds16(Xl + xb_,                &Xs_l[buf][l0]);                 \
        gload_lds16(Xl + xb_ + 16 * D_DIM,   &Xs_l[buf][l0 + 512]);           \
    } while (0)

    STAGE_C(0, 0);
    STAGE_X(0, 0);

    for (int s = 0; s < nSteps; ++s) {
        const int cur = s & 1;
        const int kt  = s & 15;
        const int ct  = s >> 4;

        if (s + 1 < nSteps) {
            STAGE_C(cur ^ 1, s + 1);          // prefetch next step (codes)
            STAGE_X(cur ^ 1, s + 1);          // prefetch next step (x)  [r6 fix]
            asm volatile("s_waitcnt vmcnt(8)" ::: "memory");  // cur staged
        } else {
            asm volatile("s_waitcnt vmcnt(0)" ::: "memory");
        }
        __builtin_amdgcn_s_barrier();          // cur buffers visible to all

        // X fragments (B operand): [nf][kh][hl]
        short8 xv[2][2][2];
#pragma unroll
        for (int nf = 0; nf < 2; ++nf) {
            xv[nf][0][0] = *(const short8*)&Xs_h[cur][(rX + nf * 32) * 32 + kOff0];
            xv[nf][1][0] = *(const short8*)&Xs_h[cur][(rX + nf * 32) * 32 + kOff1];
            xv[nf][0][1] = *(const short8*)&Xs_l[cur][(rX + nf * 32) * 32 + kOff0];
            xv[nf][1][1] = *(const short8*)&Xs_l[cur][(rX + nf * 32) * 32 + kOff1];
        }
        // code fragments (A operand) for mf 0,1
        short8 cva[2][2][2];
#pragma unroll
        for (int mf = 0; mf < 2; ++mf) {
            cva[mf][0][0] = *(const short8*)&Cs_h[cur][(rC + mf * 32) * 32 + kOff0];
            cva[mf][1][0] = *(const short8*)&Cs_h[cur][(rC + mf * 32) * 32 + kOff1];
            cva[mf][0][1] = *(const short8*)&Cs_l[cur][(rC + mf * 32) * 32 + kOff0];
            cva[mf][1][1] = *(const short8*)&Cs_l[cur][(rC + mf * 32) * 32 + kOff1];
        }

        if (kt == 0) {                          // fold previous code-tile, reset acc
            if (s) fold(ct - 1);
#pragma unroll
            for (int mf = 0; mf < 4; ++mf)
#pragma unroll
                for (int nf = 0; nf < 2; ++nf)
#pragma unroll
                    for (int r = 0; r < 16; ++r) acc[mf][nf][r] = 0.f;
        }

        __builtin_amdgcn_s_setprio(1);
#pragma unroll
        for (int kh = 0; kh < 2; ++kh)
#pragma unroll
            for (int t = 0; t < 3; ++t) {       // (c,x) = (h,h),(h,l),(l,h)
                const int tc = (t == 2) ? 1 : 0;
                const int tx = (t == 1) ? 1 : 0;
#pragma unroll
                for (int mf = 0; mf < 2; ++mf)
#pragma unroll
                    for (int nf = 0; nf < 2; ++nf)
                        acc[mf][nf] = __builtin_amdgcn_mfma_f32_32x32x16_bf16(
                            cva[mf][kh][tc], xv[nf][kh][tx], acc[mf][nf], 0, 0, 0);
            }
        __builtin_amdgcn_s_setprio(0);

        // code fragments for mf 2,3
        short8 cvb[2][2][2];
#pragma unroll
        for (int mf = 0; mf < 2; ++mf) {
            cvb[mf][0][0] = *(const short8*)&Cs_h[cur][(rC + (mf + 2) * 32) * 32 + kOff0];
            cvb[mf][1][0] = *(const short8*)&Cs_h[cur][(rC + (mf + 2) * 32) * 32 + kOff1];
            cvb[mf][0][1] = *(const short8*)&Cs_l[cur][(rC + (mf + 2) * 32) * 32 + kOff0];
            cvb[mf][1][1] = *(const short8*)&Cs_l[cur][(rC + (mf + 2) * 32) * 32 + kOff1];
        }
        asm volatile("s_waitcnt lgkmcnt(0)" ::: "memory");   // all cur reads landed
        __builtin_amdgcn_s_barrier();           // safe to stage next buffers

        __builtin_amdgcn_s_setprio(1);          // overlaps next STAGE across waves
#pragma unroll
        for (int kh = 0; kh < 2; ++kh)
#pragma unroll
            for (int t = 0; t < 3; ++t) {
                const int tc = (t == 2) ? 1 : 0;
                const int tx = (t == 1) ? 1 : 0;
#pragma unroll
                for (int mf = 0; mf < 2; ++mf)
#pragma unroll
                    for (int nf = 0; nf < 2; ++nf)
                        acc[mf + 2][nf] = __builtin_amdgcn_mfma_f32_32x32x16_bf16(
                            cvb[mf][kh][tc], xv[nf][kh][tx], acc[mf + 2][nf], 0, 0, 0);
            }
        __builtin_amdgcn_s_setprio(0);
    }
#undef STAGE_C
#undef STAGE_X

    fold(NT - 1);

    // merge lane halves (codes +-4 apart): xcol identical for l and l^32
#pragma unroll
    for (int nf = 0; nf < 2; ++nf) {
        float od1 = __shfl_xor(d1v[nf], 32);
        int   oi1 = __shfl_xor(i1v[nf], 32);
        float od2 = __shfl_xor(d2v[nf], 32);
        bool bw = (od1 < d1v[nf]) || (od1 == d1v[nf] && oi1 < i1v[nf]);
        d2v[nf] = bw ? fminf(od2, d1v[nf]) : fminf(d2v[nf], od1);
        if (bw) { d1v[nf] = od1; i1v[nf] = oi1; }
    }

    // cross-wr merge via LDS (reuse Cs_h[0]; all tile reads are done)
    __syncthreads();
    float* mD1 = (float*)&Cs_h[0][0];
    int*   mI1 = (int*)(mD1 + 256);
    float* mD2 = (float*)(mD1 + 512);
    if (wr == 1 && lane < 32) {
#pragma unroll
        for (int nf = 0; nf < 2; ++nf) {
            int x = wcq * 64 + nf * 32 + (lane & 31);
            mD1[x] = d1v[nf]; mI1[x] = i1v[nf]; mD2[x] = d2v[nf];
        }
    }
    __syncthreads();
    if (wr == 0 && lane < 32) {
#pragma unroll
        for (int nf = 0; nf < 2; ++nf) {
            int x = wcq * 64 + nf * 32 + (lane & 31);
            float od1 = mD1[x]; int oi1 = mI1[x]; float od2 = mD2[x];
            float d1 = d1v[nf]; int i1 = i1v[nf]; float d2 = d2v[nf];
            bool bw = (od1 < d1) || (od1 == d1 && oi1 < i1);
            if (bw) { d2 = fminf(od2, d1); d1 = od1; i1 = oi1; }
            else    { d2 = fminf(d2, od1); }
            size_t p = (size_t)split * N + (rowBase + x);
            pd1[p] = d1; pi1[p] = i1; pd2[p] = d2;
        }
    }
}

// ---- pass 2: merge split partials, emit index + near-tie flags ----
__global__ __launch_bounds__(256) void combine2_kernel(
        const float* __restrict__ pd1, const int* __restrict__ pi1,
        const float* __restrict__ pd2,
        int* __restrict__ out, int* __restrict__ flags, int* __restrict__ cnt,
        int N, int S) {
    int row = blockIdx.x * blockDim.x + threadIdx.x;
    if (row >= N) return;
    float d1 = pd1[row]; int i1 = pi1[row]; float d2 = pd2[row];
    for (int s = 1; s < S; ++s) {
        size_t p = (size_t)s * N + row;
        float od1 = pd1[p]; int oi1 = pi1[p]; float od2 = pd2[p];
        bool bwin = (od1 < d1) || (od1 == d1 && oi1 < i1);
        if (bwin) { d2 = fminf(od2, d1); d1 = od1; i1 = oi1; }
        else      { d2 = fminf(d2, od1); }
    }
    out[row] = i1;
    if (d2 - d1 < EPS_GAP) {
        int f = atomicAdd(cnt, 1);
        flags[f] = row;
    }
}

// ---- pass 3: exact fp32 re-solve of flagged rows (RPB rows/block) ----
__global__ __launch_bounds__(256) void refine_kernel(
        const float* __restrict__ X, const float* __restrict__ CB,
        const float* __restrict__ cbs,
        const int* __restrict__ flags, const int* __restrict__ cnt,
        int* __restrict__ out, int K) {
    __shared__ float xs[RPB][D_DIM];
    __shared__ float rD[RPB][4];
    __shared__ int   rI[RPB][4];
    const int nf = *cnt;
    for (int f0 = blockIdx.x * RPB; f0 < nf; f0 += gridDim.x * RPB) {
        const int nr = min(RPB, nf - f0);
        __syncthreads();
        for (int i = threadIdx.x; i < nr * D_DIM; i += 256)
            xs[i >> 9][i & 511] = X[(size_t)flags[f0 + (i >> 9)] * D_DIM + (i & 511)];
        __syncthreads();
        float bd[RPB]; int bi[RPB];
#pragma unroll
        for (int rr = 0; rr < RPB; ++rr) { bd[rr] = 3.4e38f; bi[rr] = 0x7fffffff; }
        for (int c = threadIdx.x; c < K; c += 256) {
            const float4* cp = (const float4*)(CB + (size_t)c * D_DIM);
            float dot[RPB];
#pragma unroll
            for (int rr = 0; rr < RPB; ++rr) dot[rr] = 0.f;
#pragma unroll 2
            for (int d = 0; d < D_DIM / 4; ++d) {
                float4 cv = cp[d];
#pragma unroll
                for (int rr = 0; rr < RPB; ++rr) {
                    float4 xv = *(const float4*)&xs[rr][d * 4];
                    dot[rr] = fmaf(xv.x, cv.x, dot[rr]);
                    dot[rr] = fmaf(xv.y, cv.y, dot[rr]);
                    dot[rr] = fmaf(xv.z, cv.z, dot[rr]);
                    dot[rr] = fmaf(xv.w, cv.w, dot[rr]);
                }
            }
            float c2v = cbs[c];
#pragma unroll
            for (int rr = 0; rr < RPB; ++rr) {
                float dist = fmaf(-2.f, dot[rr], c2v);
                if (dist < bd[rr]) { bd[rr] = dist; bi[rr] = c; }
            }
        }
#pragma unroll
        for (int rr = 0; rr < RPB; ++rr) {
            float d = bd[rr]; int i = bi[rr];
#pragma unroll
            for (int off = 1; off < 64; off <<= 1) {
                float od = __shfl_xor(d, off);
                int   oi = __shfl_xor(i, off);
                if (od < d || (od == d && oi < i)) { d = od; i = oi; }
            }
            if ((threadIdx.x & 63) == 0) {
                rD[rr][threadIdx.x >> 6] = d;
                rI[rr][threadIdx.x >> 6] = i;
            }
        }
        __syncthreads();
        if (threadIdx.x < RPB && (int)threadIdx.x < nr) {
            int rr = threadIdx.x;
            float d = rD[rr][0]; int i = rI[rr][0];
            for (int ww = 1; ww < 4; ++ww)
                if (rD[rr][ww] < d || (rD[rr][ww] == d && rI[rr][ww] < i)) {
                    d = rD[rr][ww]; i = rI[rr][ww];
                }
            out[flags[f0 + rr]] = i;
        }
    }
}

// ================= fp32 fallback (generic shapes) =================
#define BM 128
#define BN 128
#define BD 16

__global__ __launch_bounds__(256) void cbsqr_kernel(const float* __restrict__ cb,
                                                    float* __restrict__ out, int K) {
    int gtid = blockIdx.x * blockDim.x + threadIdx.x;
    int w = gtid >> 6;
    int lane = gtid & 63;
    if (w >= K) return;
    const float4* r4 = (const float4*)(cb + (size_t)w * D_DIM) + lane * 2;
    float4 u = r4[0], v = r4[1];
    float s = u.x*u.x + u.y*u.y + u.z*u.z + u.w*u.w
            + v.x*v.x + v.y*v.y + v.z*v.z + v.w*v.w;
#pragma unroll
    for (int off = 32; off; off >>= 1) s += __shfl_xor(s, off);
    if (lane == 0) out[w] = s;
}

__global__ __launch_bounds__(128) void vq_fp32_kernel(
        const float* __restrict__ X, const float* __restrict__ CB,
        const float* __restrict__ cbs,
        float* __restrict__ pd, int* __restrict__ pi,
        int* __restrict__ out, int N, int K, int nsplit) {

    __shared__ float As[BD][BM + 4];
    __shared__ float Bs[BD][BN + 4];

    const int tid = threadIdx.x;
    const int tx = tid & 7;
    const int ty = tid >> 3;
    const int rowBase = blockIdx.x * BM;
    const int split = blockIdx.y;
    const int kPer = K / nsplit;
    const int c0 = split * kPer, c1 = c0 + kPer;
    const int ldRow = tid >> 2;
    const int ldCol = (tid & 3) * 4;

    float bestD[8]; int bestI[8];
#pragma unroll
    for (int i = 0; i < 8; ++i) { bestD[i] = 3.4e38f; bestI[i] = 0; }

    for (int ct = c0; ct < c1; ct += BN) {
        float acc[8][16];
#pragma unroll
        for (int i = 0; i < 8; ++i)
#pragma unroll
            for (int j = 0; j < 16; ++j) acc[i][j] = 0.f;

        for (int dt = 0; dt < D_DIM; dt += BD) {
#pragma unroll
            for (int p = 0; p < 4; ++p) {
                int r = ldRow + p * 32;
                float4 av = *(const float4*)&X[(size_t)(rowBase + r) * D_DIM + dt + ldCol];
                float4 bv = *(const float4*)&CB[(size_t)(ct + r) * D_DIM + dt + ldCol];
                As[ldCol + 0][r] = av.x; As[ldCol + 1][r] = av.y;
                As[ldCol + 2][r] = av.z; As[ldCol + 3][r] = av.w;
                Bs[ldCol + 0][r] = bv.x; Bs[ldCol + 1][r] = bv.y;
                Bs[ldCol + 2][r] = bv.z; Bs[ldCol + 3][r] = bv.w;
            }
            __syncthreads();
#pragma unroll
            for (int d = 0; d < BD; ++d) {
                float4 a0 = *(const float4*)&As[d][ty * 4];
                float4 a1 = *(const float4*)&As[d][64 + ty * 4];
                float4 b0 = *(const float4*)&Bs[d][ 0 + tx * 4];
                float4 b1 = *(const float4*)&Bs[d][32 + tx * 4];
                float4 b2 = *(const float4*)&Bs[d][64 + tx * 4];
                float4 b3 = *(const float4*)&Bs[d][96 + tx * 4];
                float a[8] = {a0.x,a0.y,a0.z,a0.w,a1.x,a1.y,a1.z,a1.w};
                float b[16] = {b0.x,b0.y,b0.z,b0.w, b1.x,b1.y,b1.z,b1.w,
                               b2.x,b2.y,b2.z,b2.w, b3.x,b3.y,b3.z,b3.w};
#pragma unroll
                for (int i = 0; i < 8; ++i)
#pragma unroll
                    for (int j = 0; j < 16; ++j)
                        acc[i][j] = fmaf(a[i], b[j], acc[i][j]);
            }
            __syncthreads();
        }
#pragma unroll
        for (int j = 0; j < 16; ++j) {
            int code = ct + (j >> 2) * 32 + tx * 4 + (j & 3);
            float c2v = cbs[code];
#pragma unroll
            for (int i = 0; i < 8; ++i) {
                float dist = fmaf(-2.f, acc[i][j], c2v);
                if (dist < bestD[i]) { bestD[i] = dist; bestI[i] = code; }
            }
        }
    }
#pragma unroll
    for (int i = 0; i < 8; ++i) {
        float bd = bestD[i]; int bi = bestI[i];
#pragma unroll
        for (int off = 1; off < 8; off <<= 1) {
            float od = __shfl_xor(bd, off);
            int   oi = __shfl_xor(bi, off);
            if (od < bd || (od == bd && oi < bi)) { bd = od; bi = oi; }
        }
        if (tx == 0) {
            int row = rowBase + ((i < 4) ? ty * 4 + i : 64 + ty * 4 + (i - 4));
            if (nsplit == 1) out[row] = bi;
            else {
                pd[(size_t)row * nsplit + split] = bd;
                pi[(size_t)row * nsplit + split] = bi;
            }
        }
    }
}

__global__ __launch_bounds__(256) void combine_fp32_kernel(
        const float* __restrict__ pd, const int* __restrict__ pi,
        int* __restrict__ out, int N, int S) {
    int r = blockIdx.x * blockDim.x + threadIdx.x;
    if (r >= N) return;
    float bd = pd[(size_t)r * S];
    int bi = pi[(size_t)r * S];
    for (int s = 1; s < S; ++s) {
        float d = pd[(size_t)r * S + s];
        int i = pi[(size_t)r * S + s];
        if (d < bd || (d == bd && i < bi)) { bd = d; bi = i; }
    }
    out[r] = bi;
}

// =========================== launcher ===========================
extern "C" void kernel_launch(void* const* d_in, const int* in_sizes, int n_in,
                              void* d_out, int out_size, void* d_ws, size_t ws_size,
                              hipStream_t stream) {
    const float* X  = (const float*)d_in[0];
    const float* CB = (const float*)d_in[1];
    const int N = in_sizes[0] / D_DIM;
    const int K = in_sizes[1] / D_DIM;
    int* out = (int*)d_out;

    size_t o = 0;
    auto take = [&](size_t bytes) { size_t r = o; o += (bytes + 255) & ~(size_t)255; return r; };
    size_t oCbs = take((size_t)K * 4);
    size_t oXh  = take((size_t)N * D_DIM * 2);
    size_t oXl  = take((size_t)N * D_DIM * 2);
    size_t oCh  = take((size_t)K * D_DIM * 2);
    size_t oCl  = take((size_t)K * D_DIM * 2);
    size_t oPd1 = take((size_t)N * KSPLIT * 4);
    size_t oPi1 = take((size_t)N * KSPLIT * 4);
    size_t oPd2 = take((size_t)N * KSPLIT * 4);
    size_t oFlg = take((size_t)N * 4);
    size_t oCnt = take(256);
    const size_t need = o;

    char* ws = (char*)d_ws;
    float* cbs = (float*)(ws + oCbs);

    if (ws_size >= need && (N % 256) == 0 && (K % (KSPLIT * 256)) == 0) {
        unsigned short* Xh = (unsigned short*)(ws + oXh);
        unsigned short* Xl = (unsigned short*)(ws + oXl);
        unsigned short* Ch = (unsigned short*)(ws + oCh);
        unsigned short* Cl = (unsigned short*)(ws + oCl);
        float* pd1 = (float*)(ws + oPd1);
        int*   pi1 = (int*)(ws + oPi1);
        float* pd2 = (float*)(ws + oPd2);
        int* flags = (int*)(ws + oFlg);
        int* cnt   = (int*)(ws + oCnt);

        split_kernel<<<4096, 256, 0, stream>>>(X, Xh, Xl, N * D_DIM / 4);
        splitcb_kernel<<<(K + 3) / 4, 256, 0, stream>>>(CB, Ch, Cl, cbs, cnt, K);

        vq_mfma_kernel<<<(N / 256) * KSPLIT, 512, 0, stream>>>(
            Xh, Xl, Ch, Cl, cbs, pd1, pi1, pd2, N, K);
        combine2_kernel<<<(N + 255) / 256, 256, 0, stream>>>(pd1, pi1, pd2,
                                                             out, flags, cnt, N, KSPLIT);
        refine_kernel<<<256, 256, 0, stream>>>(X, CB, cbs, flags, cnt, out, K);
    } else {
        size_t base = ((size_t)K * 4 + 255) & ~(size_t)255;
        int nsplit = 4;
        while (nsplit > 1 &&
               (ws_size < base + (size_t)N * nsplit * 8 || (K % (nsplit * BN)) != 0))
            nsplit >>= 1;
        float* pd = (float*)(ws + base);
        int*   pi = (int*)(ws + base + (size_t)N * nsplit * 4);
        cbsqr_kernel<<<(K + 3) / 4, 256, 0, stream>>>(CB, cbs, K);
        dim3 grid(N / BM, nsplit);
        vq_fp32_kernel<<<grid, 128, 0, stream>>>(X, CB, cbs, pd, pi, out, N, K, nsplit);
        if (nsplit > 1)
            combine_fp32_kernel<<<(N + 255) / 256, 256, 0, stream>>>(pd, pi, out, N, nsplit);
    }
}

// Round 8
// 987.078 us; speedup vs baseline: 1.3935x; 1.3935x over previous
//
#include <hip/hip_runtime.h>

// VQ nearest-neighbor: argmin_k ||c_k||^2 - 2 x_n . c_k
// N=32768 rows, K=8192 codes, D=512, fp32 in, int32 indices out.
//
// Round 8: r7 with the vmcnt bug fixed. 8 loads staged per step ->
// steady-state outstanding at the wait = 16 (8 current + 8 next), so the
// counted wait must be vmcnt(8) (retire current step's loads), NOT
// vmcnt(16) (waits for nothing -> stale LDS reads, r7's absmax 3488).
// Keeps: quad swizzle sw(r)=((r>>1)&3)^(((r>>4)&1)<<1) (kills the
// {l,l+16,l+32,l+48} b128 bank conflict), single barrier per step
// (ds_reads provably complete before it: all results consumed by MFMAs),
// KSPLIT 4, top-3 tracking + inline exact top-2 refine, fused prep.

#define D_DIM 512
#define EPS_GAP 1.5e-6f
#define KSPLIT 4

typedef __attribute__((ext_vector_type(8))) short short8;
typedef __attribute__((ext_vector_type(16))) float f32x16;
typedef __attribute__((ext_vector_type(4))) unsigned short us4;

__device__ __forceinline__ unsigned short f2bf(float x) {
    unsigned u = __float_as_uint(x);
    u += 0x7fffu + ((u >> 16) & 1u);          // RNE
    return (unsigned short)(u >> 16);
}
__device__ __forceinline__ float bf2f(unsigned short h) {
    return __uint_as_float(((unsigned)h) << 16);
}

__device__ __forceinline__ void gload_lds16(const void* g, void* l) {
    __builtin_amdgcn_global_load_lds(
        (const __attribute__((address_space(1))) unsigned int*)g,
        (__attribute__((address_space(3))) unsigned int*)l, 16, 0, 0);
}

// insert (d,i) into a top-3 state (d3 carries no index; a merged d3 can
// never reach top-2 of a union: it is >= two elements of its own list).
__device__ __forceinline__ void ins3(float d, int i, float& d1, int& i1,
                                     float& d2, int& i2, float& d3) {
    if (d < d1 || (d == d1 && i < i1)) { d3 = d2; d2 = d1; i2 = i1; d1 = d; i1 = i; }
    else if (d < d2 || (d == d2 && i < i2)) { d3 = d2; d2 = d; i2 = i; }
    else if (d < d3) d3 = d;
}

// ---- pass 0: fused split of CB (wave/row + ||c||^2) and X (grid-stride) ----
__global__ __launch_bounds__(256) void prep_kernel(
        const float* __restrict__ X, const float* __restrict__ CB,
        unsigned short* __restrict__ Xh, unsigned short* __restrict__ Xl,
        unsigned short* __restrict__ Ch, unsigned short* __restrict__ Cl,
        float* __restrict__ cbs, int n4, int K, int cbBlocks, int xBlocks) {
    const int bid = blockIdx.x;
    const int tid = threadIdx.x;
    if (bid < cbBlocks) {
        int w = bid * 4 + (tid >> 6);
        int lane = tid & 63;
        if (w >= K) return;
        size_t base = (size_t)w * D_DIM + lane * 8;
        const float4* r4 = (const float4*)(CB + base);
        float4 u = r4[0], v = r4[1];
        float s = u.x*u.x + u.y*u.y + u.z*u.z + u.w*u.w
                + v.x*v.x + v.y*v.y + v.z*v.z + v.w*v.w;
        us4 h0, l0, h1, l1;
        h0.x = f2bf(u.x); l0.x = f2bf(u.x - bf2f(h0.x));
        h0.y = f2bf(u.y); l0.y = f2bf(u.y - bf2f(h0.y));
        h0.z = f2bf(u.z); l0.z = f2bf(u.z - bf2f(h0.z));
        h0.w = f2bf(u.w); l0.w = f2bf(u.w - bf2f(h0.w));
        h1.x = f2bf(v.x); l1.x = f2bf(v.x - bf2f(h1.x));
        h1.y = f2bf(v.y); l1.y = f2bf(v.y - bf2f(h1.y));
        h1.z = f2bf(v.z); l1.z = f2bf(v.z - bf2f(h1.z));
        h1.w = f2bf(v.w); l1.w = f2bf(v.w - bf2f(h1.w));
        ((us4*)(Ch + base))[0] = h0; ((us4*)(Ch + base))[1] = h1;
        ((us4*)(Cl + base))[0] = l0; ((us4*)(Cl + base))[1] = l1;
#pragma unroll
        for (int off = 32; off; off >>= 1) s += __shfl_xor(s, off);
        if (lane == 0) cbs[w] = s;
    } else {
        int i = (bid - cbBlocks) * 256 + tid;
        int stride = xBlocks * 256;
        for (; i < n4; i += stride) {
            float4 v = ((const float4*)X)[i];
            us4 h, l;
            h.x = f2bf(v.x); l.x = f2bf(v.x - bf2f(h.x));
            h.y = f2bf(v.y); l.y = f2bf(v.y - bf2f(h.y));
            h.z = f2bf(v.z); l.z = f2bf(v.z - bf2f(h.z));
            h.w = f2bf(v.w); l.w = f2bf(v.w - bf2f(h.w));
            ((us4*)Xh)[i] = h;
            ((us4*)Xl)[i] = l;
        }
    }
}

// ---- pass 1: transposed MFMA dists + per-lane top-3 ----
// grid = (N/256)*KSPLIT, 512 threads (8 waves: wr 2 x wcq 4).
// Output tile: 256 codes x 256 xrows. bid&3 = split (XCD-affine).
__global__ __launch_bounds__(512, 2) void vq_mfma_kernel(
        const unsigned short* __restrict__ Xh, const unsigned short* __restrict__ Xl,
        const unsigned short* __restrict__ Ch, const unsigned short* __restrict__ Cl,
        const float* __restrict__ cbs,
        float* __restrict__ pd1, int* __restrict__ pi1,
        float* __restrict__ pd2, int* __restrict__ pi2,
        float* __restrict__ pd3, int N, int K) {

    __shared__ unsigned short Cs_h[2][256 * 32], Cs_l[2][256 * 32];  // codes
    __shared__ unsigned short Xs_h[2][256 * 32], Xs_l[2][256 * 32];  // xrows

    const int tid  = threadIdx.x;
    const int lane = tid & 63;
    const int w    = tid >> 6;       // 0..7
    const int wr   = w >> 2;         // code half (0/1)
    const int wcq  = w & 3;          // x quad (0..3)
    const int bid  = blockIdx.x;
    const int split     = bid & (KSPLIT - 1);
    const int rowBase   = (bid >> 2) * 256;
    const int kPerSplit = K / KSPLIT;
    const int splitBase = split * kPerSplit;
    const int NT        = kPerSplit / 256;
    const int nSteps    = NT * 16;

    // staging: lane l covers rows w*32+(l>>2) and +16, 16B chunk p=l&3.
    // swizzle sw(r) = ((r>>1)&3) ^ (((r>>4)&1)<<1); staged rows have
    // bit4 = 0 (first gload) / 1 (second) -> src chunk differs by ^2.
    const int l4  = lane >> 2;
    const int swz = ((lane & 3) ^ ((lane >> 3) & 3)) * 8;   // elements
    const int sflip = (swz ^ 16) - swz;                      // second row set
    const size_t gX0 = (size_t)(rowBase + w * 32 + l4) * D_DIM + swz;
    const size_t gC0 = (size_t)(w * 32 + l4) * D_DIM + swz;
    const int l0 = w * 1024 + lane * 8;

    // fragment reads: row = base + (lane&31) (+mf*32: bits 1..4 unchanged),
    // k-octet c = kh*2 + (lane>>5); physical chunk = c ^ sw(row).
    const int lh = lane >> 5;
    const int rC = wr * 128 + (lane & 31);
    const int rX = wcq * 64 + (lane & 31);
    const int kp = ((lane >> 1) & 3) ^ (((lane >> 4) & 1) << 1);
    const int kOff0 = (lh ^ kp) * 8;
    const int kOff1 = kOff0 ^ 16;    // c=2+lh == (lh^2)

    float d1v[2], d2v[2], d3v[2];
    int   i1v[2], i2v[2];
#pragma unroll
    for (int nf = 0; nf < 2; ++nf) {
        d1v[nf] = 3.4e38f; d2v[nf] = 3.4e38f; d3v[nf] = 3.4e38f;
        i1v[nf] = 0x7fffffff; i2v[nf] = 0x7fffffff;
    }

    f32x16 acc[4][2];

    auto fold = [&](int ctF) {
        const int cb0 = splitBase + ctF * 256 + wr * 128 + 4 * lh;
#pragma unroll
        for (int mf = 0; mf < 4; ++mf)
#pragma unroll
            for (int rq = 0; rq < 4; ++rq) {
                float4 c2q = *(const float4*)&cbs[cb0 + mf * 32 + rq * 8];
#pragma unroll
                for (int j = 0; j < 4; ++j) {
                    const int code = cb0 + mf * 32 + rq * 8 + j;
                    const int reg  = rq * 4 + j;
                    const float c2 = (&c2q.x)[j];
#pragma unroll
                    for (int nf = 0; nf < 2; ++nf) {
                        float dist = fmaf(-2.f, acc[mf][nf][reg], c2);
                        ins3(dist, code, d1v[nf], i1v[nf], d2v[nf], i2v[nf], d3v[nf]);
                    }
                }
            }
    };

#define STAGE_C(buf, s_)                                                      \
    do { int ct_ = (s_) >> 4, kt_ = (s_) & 15;                                \
        size_t cb_ = (size_t)(splitBase + ct_ * 256) * D_DIM + gC0 + kt_ * 32;\
        gload_lds16(Ch + cb_,                        &Cs_h[buf][l0]);         \
        gload_lds16(Ch + cb_ + 16 * D_DIM + sflip,   &Cs_h[buf][l0 + 512]);   \
        gload_lds16(Cl + cb_,                        &Cs_l[buf][l0]);         \
        gload_lds16(Cl + cb_ + 16 * D_DIM + sflip,   &Cs_l[buf][l0 + 512]);   \
    } while (0)
#define STAGE_X(buf, s_)                                                      \
    do { int kt_ = (s_) & 15;                                                 \
        size_t xb_ = gX0 + kt_ * 32;                                          \
        gload_lds16(Xh + xb_,                        &Xs_h[buf][l0]);         \
        gload_lds16(Xh + xb_ + 16 * D_DIM + sflip,   &Xs_h[buf][l0 + 512]);   \
        gload_lds16(Xl + xb_,                        &Xs_l[buf][l0]);         \
        gload_lds16(Xl + xb_ + 16 * D_DIM + sflip,   &Xs_l[buf][l0 + 512]);   \
    } while (0)

    STAGE_C(0, 0);
    STAGE_X(0, 0);

    for (int s = 0; s < nSteps; ++s) {
        const int cur = s & 1;
        const int kt  = s & 15;
        const int ct  = s >> 4;

        if (s + 1 < nSteps) {
            STAGE_C(cur ^ 1, s + 1);
            STAGE_X(cur ^ 1, s + 1);
            // 8 loads/step: outstanding = 8 (cur, oldest) + 8 (next).
            // vmcnt(8) retires exactly the current step's loads.
            asm volatile("s_waitcnt vmcnt(8)" ::: "memory");
        } else {
            asm volatile("s_waitcnt vmcnt(0)" ::: "memory");
        }
        __builtin_amdgcn_s_barrier();          // cur buffers visible

        // reads + MFMAs: no manual lgkm waits -- the compiler interleaves
        // ds_read completion with MFMA issue (fine-grained lgkmcnt).
        short8 xv[2][2][2];   // [nf][kh][hl]
#pragma unroll
        for (int nf = 0; nf < 2; ++nf) {
            xv[nf][0][0] = *(const short8*)&Xs_h[cur][(rX + nf * 32) * 32 + kOff0];
            xv[nf][1][0] = *(const short8*)&Xs_h[cur][(rX + nf * 32) * 32 + kOff1];
            xv[nf][0][1] = *(const short8*)&Xs_l[cur][(rX + nf * 32) * 32 + kOff0];
            xv[nf][1][1] = *(const short8*)&Xs_l[cur][(rX + nf * 32) * 32 + kOff1];
        }
        short8 cva[2][2][2];  // mf 0,1
#pragma unroll
        for (int mf = 0; mf < 2; ++mf) {
            cva[mf][0][0] = *(const short8*)&Cs_h[cur][(rC + mf * 32) * 32 + kOff0];
            cva[mf][1][0] = *(const short8*)&Cs_h[cur][(rC + mf * 32) * 32 + kOff1];
            cva[mf][0][1] = *(const short8*)&Cs_l[cur][(rC + mf * 32) * 32 + kOff0];
            cva[mf][1][1] = *(const short8*)&Cs_l[cur][(rC + mf * 32) * 32 + kOff1];
        }

        if (kt == 0) {                          // fold prev code-tile, reset acc
            if (s) fold(ct - 1);
#pragma unroll
            for (int mf = 0; mf < 4; ++mf)
#pragma unroll
                for (int nf = 0; nf < 2; ++nf)
#pragma unroll
                    for (int r = 0; r < 16; ++r) acc[mf][nf][r] = 0.f;
        }

#pragma unroll
        for (int kh = 0; kh < 2; ++kh)
#pragma unroll
            for (int t = 0; t < 3; ++t) {       // (c,x) = (h,h),(h,l),(l,h)
                const int tc = (t == 2) ? 1 : 0;
                const int tx = (t == 1) ? 1 : 0;
#pragma unroll
                for (int mf = 0; mf < 2; ++mf)
#pragma unroll
                    for (int nf = 0; nf < 2; ++nf)
                        acc[mf][nf] = __builtin_amdgcn_mfma_f32_32x32x16_bf16(
                            cva[mf][kh][tc], xv[nf][kh][tx], acc[mf][nf], 0, 0, 0);
            }

        short8 cvb[2][2][2];  // mf 2,3
#pragma unroll
        for (int mf = 0; mf < 2; ++mf) {
            cvb[mf][0][0] = *(const short8*)&Cs_h[cur][(rC + (mf + 2) * 32) * 32 + kOff0];
            cvb[mf][1][0] = *(const short8*)&Cs_h[cur][(rC + (mf + 2) * 32) * 32 + kOff1];
            cvb[mf][0][1] = *(const short8*)&Cs_l[cur][(rC + (mf + 2) * 32) * 32 + kOff0];
            cvb[mf][1][1] = *(const short8*)&Cs_l[cur][(rC + (mf + 2) * 32) * 32 + kOff1];
        }
#pragma unroll
        for (int kh = 0; kh < 2; ++kh)
#pragma unroll
            for (int t = 0; t < 3; ++t) {
                const int tc = (t == 2) ? 1 : 0;
                const int tx = (t == 1) ? 1 : 0;
#pragma unroll
                for (int mf = 0; mf < 2; ++mf)
#pragma unroll
                    for (int nf = 0; nf < 2; ++nf)
                        acc[mf + 2][nf] = __builtin_amdgcn_mfma_f32_32x32x16_bf16(
                            cvb[mf][kh][tc], xv[nf][kh][tx], acc[mf + 2][nf], 0, 0, 0);
            }

        __builtin_amdgcn_sched_barrier(0);      // nothing crosses (pins reads)
        __builtin_amdgcn_s_barrier();           // all reads of cur done
    }
#undef STAGE_C
#undef STAGE_X

    fold(NT - 1);

    // merge lane halves (l <-> l^32): same x-col, codes offset by 4*lh
#pragma unroll
    for (int nf = 0; nf < 2; ++nf) {
        float od1 = __shfl_xor(d1v[nf], 32);
        int   oi1 = __shfl_xor(i1v[nf], 32);
        float od2 = __shfl_xor(d2v[nf], 32);
        int   oi2 = __shfl_xor(i2v[nf], 32);
        float od3 = __shfl_xor(d3v[nf], 32);
        ins3(od1, oi1, d1v[nf], i1v[nf], d2v[nf], i2v[nf], d3v[nf]);
        ins3(od2, oi2, d1v[nf], i1v[nf], d2v[nf], i2v[nf], d3v[nf]);
        d3v[nf] = fminf(d3v[nf], od3);
    }

    // cross-wr merge via LDS (reuse Cs_h[0]; loop's final barrier passed)
    __syncthreads();
    float* mD1 = (float*)&Cs_h[0][0];
    int*   mI1 = (int*)(mD1 + 256);
    float* mD2 = (float*)(mD1 + 512);
    int*   mI2 = (int*)(mD1 + 768);
    float* mD3 = (float*)(mD1 + 1024);
    if (wr == 1 && lane < 32) {
#pragma unroll
        for (int nf = 0; nf < 2; ++nf) {
            int x = wcq * 64 + nf * 32 + (lane & 31);
            mD1[x] = d1v[nf]; mI1[x] = i1v[nf];
            mD2[x] = d2v[nf]; mI2[x] = i2v[nf];
            mD3[x] = d3v[nf];
        }
    }
    __syncthreads();
    if (wr == 0 && lane < 32) {
#pragma unroll
        for (int nf = 0; nf < 2; ++nf) {
            int x = wcq * 64 + nf * 32 + (lane & 31);
            float d1 = d1v[nf], d2 = d2v[nf], d3 = d3v[nf];
            int i1 = i1v[nf], i2 = i2v[nf];
            ins3(mD1[x], mI1[x], d1, i1, d2, i2, d3);
            ins3(mD2[x], mI2[x], d1, i1, d2, i2, d3);
            d3 = fminf(d3, mD3[x]);
            size_t p = (size_t)split * N + (rowBase + x);
            pd1[p] = d1; pi1[p] = i1; pd2[p] = d2; pi2[p] = i2; pd3[p] = d3;
        }
    }
}

// ---- pass 2: merge splits + exact top-2 compare; block full scan for
// 3-way near-ties (expected ~0 rows/run). 128 rows per block.
__global__ __launch_bounds__(256) void combine_refine_kernel(
        const float* __restrict__ X, const float* __restrict__ CB,
        const float* __restrict__ cbs,
        const float* __restrict__ pd1, const int* __restrict__ pi1,
        const float* __restrict__ pd2, const int* __restrict__ pi2,
        const float* __restrict__ pd3,
        int* __restrict__ out, int N, int K, int S) {
    __shared__ float xs[D_DIM];
    __shared__ int rare[128];
    __shared__ int nrare;
    __shared__ float rDs[4];
    __shared__ int   rIs[4];
    const int tid = threadIdx.x;
    if (tid == 0) nrare = 0;
    __syncthreads();

    const int row = blockIdx.x * 128 + tid;
    if (tid < 128 && row < N) {
        float d1 = pd1[row], d2 = pd2[row], d3 = pd3[row];
        int i1 = pi1[row], i2 = pi2[row];
        for (int s = 1; s < S; ++s) {
            size_t p = (size_t)s * N + row;
            ins3(pd1[p], pi1[p], d1, i1, d2, i2, d3);
            ins3(pd2[p], pi2[p], d1, i1, d2, i2, d3);
            d3 = fminf(d3, pd3[p]);
        }
        int best = i1;
        if (d2 - d1 < EPS_GAP) {
            if (d3 - d1 < EPS_GAP) {
                int p = atomicAdd(&nrare, 1);   // shared-mem atomic
                rare[p] = row;
            } else {
                // exact fp32 top-2 compare
                const float4* xr = (const float4*)(X + (size_t)row * D_DIM);
                const float4* ca = (const float4*)(CB + (size_t)i1 * D_DIM);
                const float4* cb = (const float4*)(CB + (size_t)i2 * D_DIM);
                float dotA = 0.f, dotB = 0.f;
#pragma unroll 4
                for (int d = 0; d < D_DIM / 4; ++d) {
                    float4 xv = xr[d], av = ca[d], bv = cb[d];
                    dotA = fmaf(xv.x, av.x, dotA); dotA = fmaf(xv.y, av.y, dotA);
                    dotA = fmaf(xv.z, av.z, dotA); dotA = fmaf(xv.w, av.w, dotA);
                    dotB = fmaf(xv.x, bv.x, dotB); dotB = fmaf(xv.y, bv.y, dotB);
                    dotB = fmaf(xv.z, bv.z, dotB); dotB = fmaf(xv.w, bv.w, dotB);
                }
                float dA = fmaf(-2.f, dotA, cbs[i1]);
                float dB = fmaf(-2.f, dotB, cbs[i2]);
                best = (dB < dA || (dB == dA && i2 < i1)) ? i2 : i1;
            }
        }
        out[row] = best;
    }
    __syncthreads();
    const int nr = nrare;                       // uniform across block
    for (int r = 0; r < nr; ++r) {
        const int rrow = rare[r];
        __syncthreads();
        for (int i = tid; i < D_DIM; i += 256)
            xs[i] = X[(size_t)rrow * D_DIM + i];
        __syncthreads();
        float bd = 3.4e38f; int bi = 0x7fffffff;
        for (int c = tid; c < K; c += 256) {
            const float4* cp = (const float4*)(CB + (size_t)c * D_DIM);
            float dot = 0.f;
#pragma unroll 4
            for (int d = 0; d < D_DIM / 4; ++d) {
                float4 cv = cp[d];
                float4 xv = *(const float4*)&xs[d * 4];
                dot = fmaf(xv.x, cv.x, dot); dot = fmaf(xv.y, cv.y, dot);
                dot = fmaf(xv.z, cv.z, dot); dot = fmaf(xv.w, cv.w, dot);
            }
            float dist = fmaf(-2.f, dot, cbs[c]);
            if (dist < bd) { bd = dist; bi = c; }
        }
#pragma unroll
        for (int off = 1; off < 64; off <<= 1) {
            float od = __shfl_xor(bd, off);
            int   oi = __shfl_xor(bi, off);
            if (od < bd || (od == bd && oi < bi)) { bd = od; bi = oi; }
        }
        if ((tid & 63) == 0) { rDs[tid >> 6] = bd; rIs[tid >> 6] = bi; }
        __syncthreads();
        if (tid == 0) {
            for (int ww = 1; ww < 4; ++ww)
                if (rDs[ww] < bd || (rDs[ww] == bd && rIs[ww] < bi)) {
                    bd = rDs[ww]; bi = rIs[ww];
                }
            out[rrow] = bi;
        }
    }
}

// ================= fp32 fallback (generic shapes) =================
#define BM 128
#define BN 128
#define BD 16

__global__ __launch_bounds__(256) void cbsqr_kernel(const float* __restrict__ cb,
                                                    float* __restrict__ out, int K) {
    int gtid = blockIdx.x * blockDim.x + threadIdx.x;
    int w = gtid >> 6;
    int lane = gtid & 63;
    if (w >= K) return;
    const float4* r4 = (const float4*)(cb + (size_t)w * D_DIM) + lane * 2;
    float4 u = r4[0], v = r4[1];
    float s = u.x*u.x + u.y*u.y + u.z*u.z + u.w*u.w
            + v.x*v.x + v.y*v.y + v.z*v.z + v.w*v.w;
#pragma unroll
    for (int off = 32; off; off >>= 1) s += __shfl_xor(s, off);
    if (lane == 0) out[w] = s;
}

__global__ __launch_bounds__(128) void vq_fp32_kernel(
        const float* __restrict__ X, const float* __restrict__ CB,
        const float* __restrict__ cbs,
        float* __restrict__ pd, int* __restrict__ pi,
        int* __restrict__ out, int N, int K, int nsplit) {

    __shared__ float As[BD][BM + 4];
    __shared__ float Bs[BD][BN + 4];

    const int tid = threadIdx.x;
    const int tx = tid & 7;
    const int ty = tid >> 3;
    const int rowBase = blockIdx.x * BM;
    const int split = blockIdx.y;
    const int kPer = K / nsplit;
    const int c0 = split * kPer, c1 = c0 + kPer;
    const int ldRow = tid >> 2;
    const int ldCol = (tid & 3) * 4;

    float bestD[8]; int bestI[8];
#pragma unroll
    for (int i = 0; i < 8; ++i) { bestD[i] = 3.4e38f; bestI[i] = 0; }

    for (int ct = c0; ct < c1; ct += BN) {
        float acc[8][16];
#pragma unroll
        for (int i = 0; i < 8; ++i)
#pragma unroll
            for (int j = 0; j < 16; ++j) acc[i][j] = 0.f;

        for (int dt = 0; dt < D_DIM; dt += BD) {
#pragma unroll
            for (int p = 0; p < 4; ++p) {
                int r = ldRow + p * 32;
                float4 av = *(const float4*)&X[(size_t)(rowBase + r) * D_DIM + dt + ldCol];
                float4 bv = *(const float4*)&CB[(size_t)(ct + r) * D_DIM + dt + ldCol];
                As[ldCol + 0][r] = av.x; As[ldCol + 1][r] = av.y;
                As[ldCol + 2][r] = av.z; As[ldCol + 3][r] = av.w;
                Bs[ldCol + 0][r] = bv.x; Bs[ldCol + 1][r] = bv.y;
                Bs[ldCol + 2][r] = bv.z; Bs[ldCol + 3][r] = bv.w;
            }
            __syncthreads();
#pragma unroll
            for (int d = 0; d < BD; ++d) {
                float4 a0 = *(const float4*)&As[d][ty * 4];
                float4 a1 = *(const float4*)&As[d][64 + ty * 4];
                float4 b0 = *(const float4*)&Bs[d][ 0 + tx * 4];
                float4 b1 = *(const float4*)&Bs[d][32 + tx * 4];
                float4 b2 = *(const float4*)&Bs[d][64 + tx * 4];
                float4 b3 = *(const float4*)&Bs[d][96 + tx * 4];
                float a[8] = {a0.x,a0.y,a0.z,a0.w,a1.x,a1.y,a1.z,a1.w};
                float b[16] = {b0.x,b0.y,b0.z,b0.w, b1.x,b1.y,b1.z,b1.w,
                               b2.x,b2.y,b2.z,b2.w, b3.x,b3.y,b3.z,b3.w};
#pragma unroll
                for (int i = 0; i < 8; ++i)
#pragma unroll
                    for (int j = 0; j < 16; ++j)
                        acc[i][j] = fmaf(a[i], b[j], acc[i][j]);
            }
            __syncthreads();
        }
#pragma unroll
        for (int j = 0; j < 16; ++j) {
            int code = ct + (j >> 2) * 32 + tx * 4 + (j & 3);
            float c2v = cbs[code];
#pragma unroll
            for (int i = 0; i < 8; ++i) {
                float dist = fmaf(-2.f, acc[i][j], c2v);
                if (dist < bestD[i]) { bestD[i] = dist; bestI[i] = code; }
            }
        }
    }
#pragma unroll
    for (int i = 0; i < 8; ++i) {
        float bd = bestD[i]; int bi = bestI[i];
#pragma unroll
        for (int off = 1; off < 8; off <<= 1) {
            float od = __shfl_xor(bd, off);
            int   oi = __shfl_xor(bi, off);
            if (od < bd || (od == bd && oi < bi)) { bd = od; bi = oi; }
        }
        if (tx == 0) {
            int row = rowBase + ((i < 4) ? ty * 4 + i : 64 + ty * 4 + (i - 4));
            if (nsplit == 1) out[row] = bi;
            else {
                pd[(size_t)row * nsplit + split] = bd;
                pi[(size_t)row * nsplit + split] = bi;
            }
        }
    }
}

__global__ __launch_bounds__(256) void combine_fp32_kernel(
        const float* __restrict__ pd, const int* __restrict__ pi,
        int* __restrict__ out, int N, int S) {
    int r = blockIdx.x * blockDim.x + threadIdx.x;
    if (r >= N) return;
    float bd = pd[(size_t)r * S];
    int bi = pi[(size_t)r * S];
    for (int s = 1; s < S; ++s) {
        float d = pd[(size_t)r * S + s];
        int i = pi[(size_t)r * S + s];
        if (d < bd || (d == bd && i < bi)) { bd = d; bi = i; }
    }
    out[r] = bi;
}

// =========================== launcher ===========================
extern "C" void kernel_launch(void* const* d_in, const int* in_sizes, int n_in,
                              void* d_out, int out_size, void* d_ws, size_t ws_size,
                              hipStream_t stream) {
    const float* X  = (const float*)d_in[0];
    const float* CB = (const float*)d_in[1];
    const int N = in_sizes[0] / D_DIM;
    const int K = in_sizes[1] / D_DIM;
    int* out = (int*)d_out;

    size_t o = 0;
    auto take = [&](size_t bytes) { size_t r = o; o += (bytes + 255) & ~(size_t)255; return r; };
    size_t oCbs = take((size_t)K * 4);
    size_t oXh  = take((size_t)N * D_DIM * 2);
    size_t oXl  = take((size_t)N * D_DIM * 2);
    size_t oCh  = take((size_t)K * D_DIM * 2);
    size_t oCl  = take((size_t)K * D_DIM * 2);
    size_t oPd1 = take((size_t)N * KSPLIT * 4);
    size_t oPi1 = take((size_t)N * KSPLIT * 4);
    size_t oPd2 = take((size_t)N * KSPLIT * 4);
    size_t oPi2 = take((size_t)N * KSPLIT * 4);
    size_t oPd3 = take((size_t)N * KSPLIT * 4);
    const size_t need = o;

    char* ws = (char*)d_ws;
    float* cbs = (float*)(ws + oCbs);

    if (ws_size >= need && (N % 256) == 0 && (K % (KSPLIT * 256)) == 0) {
        unsigned short* Xh = (unsigned short*)(ws + oXh);
        unsigned short* Xl = (unsigned short*)(ws + oXl);
        unsigned short* Ch = (unsigned short*)(ws + oCh);
        unsigned short* Cl = (unsigned short*)(ws + oCl);
        float* pd1 = (float*)(ws + oPd1);
        int*   pi1 = (int*)(ws + oPi1);
        float* pd2 = (float*)(ws + oPd2);
        int*   pi2 = (int*)(ws + oPi2);
        float* pd3 = (float*)(ws + oPd3);

        const int cbBlocks = K / 4;
        const int xBlocks  = 2048;
        prep_kernel<<<cbBlocks + xBlocks, 256, 0, stream>>>(
            X, CB, Xh, Xl, Ch, Cl, cbs, N * D_DIM / 4, K, cbBlocks, xBlocks);

        vq_mfma_kernel<<<(N / 256) * KSPLIT, 512, 0, stream>>>(
            Xh, Xl, Ch, Cl, cbs, pd1, pi1, pd2, pi2, pd3, N, K);

        combine_refine_kernel<<<N / 128, 256, 0, stream>>>(
            X, CB, cbs, pd1, pi1, pd2, pi2, pd3, out, N, K, KSPLIT);
    } else {
        size_t base = ((size_t)K * 4 + 255) & ~(size_t)255;
        int nsplit = 4;
        while (nsplit > 1 &&
               (ws_size < base + (size_t)N * nsplit * 8 || (K % (nsplit * BN)) != 0))
            nsplit >>= 1;
        float* pd = (float*)(ws + base);
        int*   pi = (int*)(ws + base + (size_t)N * nsplit * 4);
        cbsqr_kernel<<<(K + 3) / 4, 256, 0, stream>>>(CB, cbs, K);
        dim3 grid(N / BM, nsplit);
        vq_fp32_kernel<<<grid, 128, 0, stream>>>(X, CB, cbs, pd, pi, out, N, K, nsplit);
        if (nsplit > 1)
            combine_fp32_kernel<<<(N + 255) / 256, 256, 0, stream>>>(pd, pi, out, N, nsplit);
    }
}